// Round 7
// baseline (911.755 us; speedup 1.0000x reference)
//
#include <hip/hip_runtime.h>
#include <hip/hip_bf16.h>
#include <hip/hip_fp16.h>

#define NNODES 60000
#define NREL   70
#define NB     30
#define NEDGE  1920000
#define NBLK   235      // ceil(NNODES/256)

// ---------------- CSR build (both directions) ----------------

__global__ void hist2_kernel(const int* __restrict__ src, const int* __restrict__ dst,
                             int* __restrict__ cntS, int* __restrict__ cntD) {
    int e = blockIdx.x * blockDim.x + threadIdx.x;
    if (e < NEDGE) {
        atomicAdd(&cntD[dst[e]], 1);
        atomicAdd(&cntS[src[e]], 1);
    }
}

// hierarchical exclusive scan: A) per-block sums, B) scan partials, C) final
__global__ void scanA_kernel(const int* __restrict__ cnt, int* __restrict__ bsum) {
    __shared__ int lds[256];
    int i = blockIdx.x * 256 + threadIdx.x;
    int v = (i < NNODES) ? cnt[i] : 0;
    lds[threadIdx.x] = v;
    __syncthreads();
    for (int d = 128; d > 0; d >>= 1) {
        if (threadIdx.x < d) lds[threadIdx.x] += lds[threadIdx.x + d];
        __syncthreads();
    }
    if (threadIdx.x == 0) bsum[blockIdx.x] = lds[0];
}

__global__ void scanB_kernel(const int* __restrict__ bsum, int* __restrict__ boff) {
    __shared__ int lds[256];
    int v = (threadIdx.x < NBLK) ? bsum[threadIdx.x] : 0;
    lds[threadIdx.x] = v;
    __syncthreads();
    for (int d = 1; d < 256; d <<= 1) {
        int t = (threadIdx.x >= d) ? lds[threadIdx.x - d] : 0;
        __syncthreads();
        lds[threadIdx.x] += t;
        __syncthreads();
    }
    boff[threadIdx.x] = lds[threadIdx.x] - v;   // exclusive
}

__global__ void scanC_kernel(const int* __restrict__ cnt, const int* __restrict__ boff,
                             int* __restrict__ offs) {
    __shared__ int lds[256];
    int i = blockIdx.x * 256 + threadIdx.x;
    int v = (i < NNODES) ? cnt[i] : 0;
    lds[threadIdx.x] = v;
    __syncthreads();
    for (int d = 1; d < 256; d <<= 1) {
        int t = (threadIdx.x >= d) ? lds[threadIdx.x - d] : 0;
        __syncthreads();
        lds[threadIdx.x] += t;
        __syncthreads();
    }
    if (i < NNODES) offs[i] = boff[blockIdx.x] + lds[threadIdx.x] - v;
}

// mode==1 (stream): ebufS payload = (et<<25) | dstslot   (slot < 2^25, et < 2^7)
// mode==0 (atomic): ebufS payload = (et<<16) | dst
__global__ void fill2_kernel(const int* __restrict__ src, const int* __restrict__ dst,
                             const int* __restrict__ et,
                             const int* __restrict__ offsS, const int* __restrict__ offsD,
                             int* __restrict__ curS, int* __restrict__ curD,
                             int* __restrict__ ebufS, int* __restrict__ ebufD, int mode) {
    int e = blockIdx.x * blockDim.x + threadIdx.x;
    if (e < NEDGE) {
        int s = src[e], d = dst[e], t = et[e];
        int pD = atomicAdd(&curD[d], 1);
        int slot = offsD[d] + pD;
        ebufD[slot] = (t << 16) | s;            // by-dst: payload (et, src)
        int pS = atomicAdd(&curS[s], 1);
        int payload = mode ? ((t << 25) | slot) : ((t << 16) | d);
        ebufS[offsS[s] + pS] = payload;
    }
}

// ---------------- weight expansion ----------------

// w2t[r][o][i] = sum_b att2[r,b] * basis2[b][i][o]   (transposed for float4 reads)
__global__ void wexpand2_kernel(const float* __restrict__ att, const float* __restrict__ basis,
                                float* __restrict__ w2t) {
    int idx = blockIdx.x * blockDim.x + threadIdx.x;
    if (idx >= NREL * 256) return;
    int r = idx >> 8, t = idx & 255, o = t >> 5, i = t & 31;
    float s = 0.f;
    #pragma unroll
    for (int b = 0; b < NB; ++b) s += att[r * NB + b] * basis[b * 256 + i * 8 + o];
    w2t[r * 256 + o * 32 + i] = s;
}

// w3[r][i] = sum_b att3[r,b] * basis3[b][i][0]
__global__ void wexpand3_kernel(const float* __restrict__ att, const float* __restrict__ basis,
                                float* __restrict__ w3) {
    int idx = blockIdx.x * blockDim.x + threadIdx.x;
    if (idx >= NREL * 8) return;
    int r = idx >> 3, i = idx & 7;
    float s = 0.f;
    #pragma unroll
    for (int b = 0; b < NB; ++b) s += att[r * NB + b] * basis[b * 8 + i];
    w3[idx] = s;
}

// ---------------- layer 1, stream path ----------------

__global__ void layer1_scatter_stream_kernel(const int* __restrict__ ebufS,
                                             const int* __restrict__ offsS,
                                             const int* __restrict__ cntS,
                                             const float* __restrict__ att1,
                                             const float* __restrict__ basis1,
                                             unsigned short* __restrict__ msgh) {
    __shared__ float att_lds[NREL * 32];   // padded rows of 32 for b128 reads
    for (int i = threadIdx.x; i < NREL * NB; i += 256) {
        int r = i / NB, b = i - r * NB;
        att_lds[r * 32 + b] = att1[i];
    }
    __syncthreads();
    int wave = threadIdx.x >> 6, lane = threadIdx.x & 63;
    int s = blockIdx.x * 4 + wave;           // NNODES % 4 == 0
    int o = lane & 31, half = lane >> 5;
    int off = offsS[s], c = cntS[s];
    if (c == 0) return;
    float B[NB];
    const float* bp = basis1 + (size_t)s * 32 + o;
    #pragma unroll
    for (int b = 0; b < NB; ++b) B[b] = bp[(size_t)b * (NNODES * 32)];
    for (int k = half; k < c; k += 2) {
        unsigned p = (unsigned)ebufS[off + k];
        int slot = p & 0x01FFFFFF;
        int et   = p >> 25;
        const float* ar = att_lds + et * 32;   // wave-uniform per half -> broadcast
        float m = 0.f;
        #pragma unroll
        for (int b = 0; b < NB; ++b) m = fmaf(ar[b], B[b], m);
        msgh[(size_t)slot * 32 + o] = __half_as_ushort(__float2half_rn(m));
    }
}

__global__ void layer1_reduce_kernel(const unsigned short* __restrict__ msgh,
                                     const int* __restrict__ offsD, const int* __restrict__ cntD,
                                     const float* __restrict__ root1,
                                     const float* __restrict__ bias1,
                                     float* __restrict__ x1) {
    int wave = threadIdx.x >> 6, lane = threadIdx.x & 63;
    int n = blockIdx.x * 4 + wave;
    int o2 = (lane & 15) * 2, grp = lane >> 4;   // 4 slots in flight per wave
    int off = offsD[n], c = cntD[n];
    float acc0 = 0.f, acc1 = 0.f;
    for (int k = grp; k < c; k += 4) {
        __half2 h = *reinterpret_cast<const __half2*>(msgh + (size_t)(off + k) * 32 + o2);
        float2 f = __half22float2(h);
        acc0 += f.x; acc1 += f.y;
    }
    acc0 += __shfl_xor(acc0, 16); acc0 += __shfl_xor(acc0, 32);
    acc1 += __shfl_xor(acc1, 16); acc1 += __shfl_xor(acc1, 32);
    if (grp == 0) {
        float inv = 1.0f / fmaxf((float)c, 1.0f);
        size_t base = (size_t)n * 32 + o2;
        x1[base]     = fmaxf(acc0 * inv + root1[base]     + bias1[o2],     0.f);
        x1[base + 1] = fmaxf(acc1 * inv + root1[base + 1] + bias1[o2 + 1], 0.f);
    }
}

// ---------------- layer 1, atomic fallback ----------------

__global__ void layer1_scatter_kernel(const int* __restrict__ ebufS, const int* __restrict__ offsS,
                                      const int* __restrict__ cntS, const float* __restrict__ att1,
                                      const float* __restrict__ basis1, float* __restrict__ x1acc) {
    int wave = threadIdx.x >> 6, lane = threadIdx.x & 63;
    int s = blockIdx.x * 4 + wave;
    int o = lane & 31, half = lane >> 5;
    int off = offsS[s], c = cntS[s];
    if (c == 0) return;
    float B[NB];
    const float* bp = basis1 + (size_t)s * 32 + o;
    #pragma unroll
    for (int b = 0; b < NB; ++b) B[b] = bp[(size_t)b * (NNODES * 32)];
    for (int k = half; k < c; k += 2) {
        int p  = ebufS[off + k];
        int d  = p & 0xFFFF, et = p >> 16;
        float attv = (o < NB) ? att1[et * NB + o] : 0.f;
        float m = 0.f;
        #pragma unroll
        for (int b = 0; b < NB; ++b) {
            float a = __shfl(attv, (lane & 32) + b);
            m = fmaf(a, B[b], m);
        }
        atomicAdd(&x1acc[(size_t)d * 32 + o], m);
    }
}

__global__ void layer1_finalize_kernel(const int* __restrict__ cntD,
                                       const float* __restrict__ root1,
                                       const float* __restrict__ bias1,
                                       float* __restrict__ x1) {
    int i = blockIdx.x * 256 + threadIdx.x;
    if (i >= NNODES * 32) return;
    int n = i >> 5, o = i & 31;
    float c = (float)cntD[n];
    float v = x1[i] / fmaxf(c, 1.0f) + root1[i] + bias1[o];
    x1[i] = fmaxf(v, 0.0f);
}

// ---------------- layer 2, edge-parallel: msg + reduce ----------------
// A: thread = (slot, o); msg2[slot*8+o] = dot(x1[src], w2t[et][o])

__global__ void layer2_msg_kernel(const int* __restrict__ ebufD,
                                  const float* __restrict__ x1, const float* __restrict__ w2t,
                                  float* __restrict__ msg2) {
    int t = blockIdx.x * 256 + threadIdx.x;
    int slot = t >> 3, o = t & 7;
    if (slot >= NEDGE) return;
    int p = ebufD[slot];
    int src = p & 0xFFFF, et = p >> 16;
    const float4* xp = (const float4*)(x1 + (size_t)src * 32);
    const float4* wp = (const float4*)(w2t + et * 256 + o * 32);
    float acc = 0.f;
    #pragma unroll
    for (int i = 0; i < 8; ++i) {
        float4 xv = xp[i], wv = wp[i];
        acc += xv.x * wv.x + xv.y * wv.y + xv.z * wv.z + xv.w * wv.w;
    }
    msg2[t] = acc;   // coalesced
}

// B: wave per node; o = lane&7, grp = lane>>3 (8 slots in flight, 256 B/wave coalesced)
__global__ void layer2_reduce_kernel(const float* __restrict__ msg2,
                                     const int* __restrict__ offsD, const int* __restrict__ cntD,
                                     const float* __restrict__ x1,
                                     const float* __restrict__ root2, const float* __restrict__ bias2,
                                     float* __restrict__ x2) {
    int wave = threadIdx.x >> 6, lane = threadIdx.x & 63;
    int n = blockIdx.x * 4 + wave;
    int o = lane & 7, grp = lane >> 3;
    int off = offsD[n], c = cntD[n];
    float acc = 0.f;
    for (int k = grp; k < c; k += 8) acc += msg2[(size_t)(off + k) * 8 + o];
    #pragma unroll
    for (int d = 8; d < 64; d <<= 1) acc += __shfl_xor(acc, d);
    if (lane < 8) {
        float self = 0.f;
        const float* xn = x1 + (size_t)n * 32;
        #pragma unroll
        for (int i = 0; i < 32; ++i) self += xn[i] * root2[i * 8 + o];
        float v = acc / fmaxf((float)c, 1.0f) + self + bias2[o];
        x2[(size_t)n * 8 + o] = fmaxf(v, 0.0f);
    }
}

// ---------------- layer 3, edge-parallel: msg + reduce ----------------

__global__ void layer3_msg_kernel(const int* __restrict__ ebufD,
                                  const float* __restrict__ x2, const float* __restrict__ w3,
                                  float* __restrict__ msg3) {
    int slot = blockIdx.x * 256 + threadIdx.x;
    if (slot >= NEDGE) return;
    int p = ebufD[slot];
    int src = p & 0xFFFF, et = p >> 16;
    const float4* xp = (const float4*)(x2 + (size_t)src * 8);
    const float4* wp = (const float4*)(w3 + et * 8);
    float4 a0 = xp[0], a1 = xp[1], b0 = wp[0], b1 = wp[1];
    msg3[slot] = a0.x * b0.x + a0.y * b0.y + a0.z * b0.z + a0.w * b0.w
               + a1.x * b1.x + a1.y * b1.y + a1.z * b1.z + a1.w * b1.w;
}

__global__ void layer3_reduce_kernel(const float* __restrict__ msg3,
                                     const int* __restrict__ offsD, const int* __restrict__ cntD,
                                     const float* __restrict__ x2,
                                     const float* __restrict__ w3unused,
                                     const float* __restrict__ root3, const float* __restrict__ bias3,
                                     float* __restrict__ out) {
    int wave = threadIdx.x >> 6, lane = threadIdx.x & 63;
    int n = blockIdx.x * 4 + wave;
    int off = offsD[n], c = cntD[n];
    float acc = 0.f;
    for (int k = lane; k < c; k += 64) acc += msg3[off + k];
    #pragma unroll
    for (int d = 1; d < 64; d <<= 1) acc += __shfl_xor(acc, d);
    if (lane == 0) {
        float self = 0.f;
        const float* xn = x2 + (size_t)n * 8;
        #pragma unroll
        for (int i = 0; i < 8; ++i) self += xn[i] * root3[i];
        out[n] = acc / fmaxf((float)c, 1.0f) + self + bias3[0];
    }
}

// ---------------- legacy per-node layers 2/3 (fallback) ----------------

__global__ void layer2_kernel(const int* __restrict__ ebufD, const int* __restrict__ offsD,
                              const int* __restrict__ cntD,
                              const float* __restrict__ x1, const float* __restrict__ w2t,
                              const float* __restrict__ root2, const float* __restrict__ bias2,
                              float* __restrict__ x2) {
    int wave = threadIdx.x >> 6, lane = threadIdx.x & 63;
    int n = blockIdx.x * 4 + wave;
    int o = lane & 7, slot = lane >> 3;
    int off = offsD[n], c = cntD[n];
    float acc = 0.f;
    for (int k0 = 0; k0 < c; k0 += 8) {
        int kk = k0 + slot;
        if (kk < c) {
            int packed = ebufD[off + kk];
            int src = packed & 0xFFFF, et = packed >> 16;
            const float4* xp = (const float4*)(x1 + (size_t)src * 32);
            const float4* wp = (const float4*)(w2t + et * 256 + o * 32);
            #pragma unroll
            for (int i = 0; i < 8; ++i) {
                float4 xv = xp[i], wv = wp[i];
                acc += xv.x * wv.x + xv.y * wv.y + xv.z * wv.z + xv.w * wv.w;
            }
        }
    }
    #pragma unroll
    for (int d = 8; d < 64; d <<= 1) acc += __shfl_xor(acc, d);
    if (lane < 8) {
        float self = 0.f;
        const float* xn = x1 + (size_t)n * 32;
        #pragma unroll
        for (int i = 0; i < 32; ++i) self += xn[i] * root2[i * 8 + o];
        float v = acc / fmaxf((float)c, 1.0f) + self + bias2[o];
        x2[(size_t)n * 8 + o] = fmaxf(v, 0.0f);
    }
}

__global__ void layer3_kernel(const int* __restrict__ ebufD, const int* __restrict__ offsD,
                              const int* __restrict__ cntD,
                              const float* __restrict__ x2, const float* __restrict__ w3,
                              const float* __restrict__ root3, const float* __restrict__ bias3,
                              float* __restrict__ out) {
    int wave = threadIdx.x >> 6, lane = threadIdx.x & 63;
    int n = blockIdx.x * 4 + wave;
    int off = offsD[n], c = cntD[n];
    float acc = 0.f;
    for (int k = lane; k < c; k += 64) {
        int packed = ebufD[off + k];
        int src = packed & 0xFFFF, et = packed >> 16;
        const float4* xp = (const float4*)(x2 + src * 8);
        const float4* wp = (const float4*)(w3 + et * 8);
        float4 a0 = xp[0], a1 = xp[1], b0 = wp[0], b1 = wp[1];
        acc += a0.x * b0.x + a0.y * b0.y + a0.z * b0.z + a0.w * b0.w
             + a1.x * b1.x + a1.y * b1.y + a1.z * b1.z + a1.w * b1.w;
    }
    #pragma unroll
    for (int d = 1; d < 64; d <<= 1) acc += __shfl_xor(acc, d);
    if (lane == 0) {
        float self = 0.f;
        const float* xn = x2 + (size_t)n * 8;
        #pragma unroll
        for (int i = 0; i < 8; ++i) self += xn[i] * root3[i];
        out[n] = acc / fmaxf((float)c, 1.0f) + self + bias3[0];
    }
}

// ---------------- launch ----------------

extern "C" void kernel_launch(void* const* d_in, const int* in_sizes, int n_in,
                              void* d_out, int out_size, void* d_ws, size_t ws_size,
                              hipStream_t stream) {
    const int*   edge_index = (const int*)  d_in[0];
    const int*   edge_type  = (const int*)  d_in[1];
    const float* att1   = (const float*) d_in[2];
    const float* basis1 = (const float*) d_in[3];
    const float* root1  = (const float*) d_in[4];
    const float* bias1  = (const float*) d_in[5];
    const float* att2   = (const float*) d_in[6];
    const float* basis2 = (const float*) d_in[7];
    const float* root2  = (const float*) d_in[8];
    const float* bias2  = (const float*) d_in[9];
    const float* att3   = (const float*) d_in[10];
    const float* basis3 = (const float*) d_in[11];
    const float* root3  = (const float*) d_in[12];
    const float* bias3  = (const float*) d_in[13];
    float* out = (float*)d_out;

    const int* srcArr = edge_index;
    const int* dstArr = edge_index + NEDGE;

    char* ws = (char*)d_ws;
    int*   cntS   = (int*)(ws + 0);              // 240,000
    int*   cntD   = (int*)(ws + 240128);         // 240,000
    int*   offsS  = (int*)(ws + 480256);         // 240,000
    int*   offsD  = (int*)(ws + 720384);         // 240,000
    int*   bsum   = (int*)(ws + 960512);         // 1,024
    int*   boff   = (int*)(ws + 961536);         // 1,024
    int*   curS   = (int*)(ws + 962560);         // 240,000
    int*   curD   = (int*)(ws + 1202688);        // 240,000
    int*   ebufS  = (int*)(ws + 1442816);        // 7,680,000
    int*   ebufD  = (int*)(ws + 9122816);        // 7,680,000
    float* w2t    = (float*)(ws + 16802816);     // 71,680
    float* w3     = (float*)(ws + 16874496);     // 2,240
    float* x1     = (float*)(ws + 16877056);     // 7,680,000
    float* x2     = (float*)(ws + 24557056);     // 1,920,000  -> end 26,477,056
    unsigned short* msgh = (unsigned short*)(ws + 26477056);  // 122,880,000 -> end 149,357,056
    float* msg2   = (float*)(ws + 26477056);     // 61,440,000 (reuses msgh region after l1 reduce)
    float* msg3   = (float*)(ws + 87917056);     // 7,680,000  -> end 95,597,056
    const bool use_stream = ws_size >= 149357056ULL;

    // zero histograms + cursors
    hipMemsetAsync(ws, 0, 480128, stream);              // cntS + cntD
    hipMemsetAsync(ws + 962560, 0, 480128, stream);     // curS + curD

    // CSR build (both directions)
    hist2_kernel<<<NEDGE / 256, 256, 0, stream>>>(srcArr, dstArr, cntS, cntD);
    scanA_kernel<<<NBLK, 256, 0, stream>>>(cntS, bsum);
    scanB_kernel<<<1, 256, 0, stream>>>(bsum, boff);
    scanC_kernel<<<NBLK, 256, 0, stream>>>(cntS, boff, offsS);
    scanA_kernel<<<NBLK, 256, 0, stream>>>(cntD, bsum);
    scanB_kernel<<<1, 256, 0, stream>>>(bsum, boff);
    scanC_kernel<<<NBLK, 256, 0, stream>>>(cntD, boff, offsD);
    fill2_kernel<<<NEDGE / 256, 256, 0, stream>>>(srcArr, dstArr, edge_type,
                                                  offsS, offsD, curS, curD, ebufS, ebufD,
                                                  use_stream ? 1 : 0);

    // weight expansion
    wexpand2_kernel<<<(NREL * 256 + 255) / 256, 256, 0, stream>>>(att2, basis2, w2t);
    wexpand3_kernel<<<(NREL * 8 + 255) / 256, 256, 0, stream>>>(att3, basis3, w3);

    // layer 1
    if (use_stream) {
        layer1_scatter_stream_kernel<<<NNODES / 4, 256, 0, stream>>>(ebufS, offsS, cntS,
                                                                     att1, basis1, msgh);
        layer1_reduce_kernel<<<NNODES / 4, 256, 0, stream>>>(msgh, offsD, cntD, root1, bias1, x1);
    } else {
        hipMemsetAsync((void*)x1, 0, 7680000, stream);
        layer1_scatter_kernel<<<NNODES / 4, 256, 0, stream>>>(ebufS, offsS, cntS, att1, basis1, x1);
        layer1_finalize_kernel<<<(NNODES * 32) / 256, 256, 0, stream>>>(cntD, root1, bias1, x1);
    }

    // layers 2, 3
    if (use_stream) {
        layer2_msg_kernel<<<(NEDGE * 8) / 256, 256, 0, stream>>>(ebufD, x1, w2t, msg2);
        layer2_reduce_kernel<<<NNODES / 4, 256, 0, stream>>>(msg2, offsD, cntD, x1, root2, bias2, x2);
        layer3_msg_kernel<<<NEDGE / 256, 256, 0, stream>>>(ebufD, x2, w3, msg3);
        layer3_reduce_kernel<<<NNODES / 4, 256, 0, stream>>>(msg3, offsD, cntD, x2, w3, root3, bias3, out);
    } else {
        layer2_kernel<<<NNODES / 4, 256, 0, stream>>>(ebufD, offsD, cntD, x1, w2t, root2, bias2, x2);
        layer3_kernel<<<NNODES / 4, 256, 0, stream>>>(ebufD, offsD, cntD, x2, w3, root3, bias3, out);
    }
}

// Round 8
// 891.709 us; speedup vs baseline: 1.0225x; 1.0225x over previous
//
#include <hip/hip_runtime.h>
#include <hip/hip_bf16.h>
#include <hip/hip_fp16.h>

#define NNODES 60000
#define NREL   70
#define NB     30
#define NEDGE  1920000
#define NBLK   235      // ceil(NNODES/256)

// ---------------- CSR build (both directions) ----------------

__global__ void hist2_kernel(const int* __restrict__ src, const int* __restrict__ dst,
                             int* __restrict__ cntS, int* __restrict__ cntD) {
    int e = blockIdx.x * blockDim.x + threadIdx.x;
    if (e < NEDGE) {
        atomicAdd(&cntD[dst[e]], 1);
        atomicAdd(&cntS[src[e]], 1);
    }
}

__global__ void scanA_kernel(const int* __restrict__ cnt, int* __restrict__ bsum) {
    __shared__ int lds[256];
    int i = blockIdx.x * 256 + threadIdx.x;
    int v = (i < NNODES) ? cnt[i] : 0;
    lds[threadIdx.x] = v;
    __syncthreads();
    for (int d = 128; d > 0; d >>= 1) {
        if (threadIdx.x < d) lds[threadIdx.x] += lds[threadIdx.x + d];
        __syncthreads();
    }
    if (threadIdx.x == 0) bsum[blockIdx.x] = lds[0];
}

__global__ void scanB_kernel(const int* __restrict__ bsum, int* __restrict__ boff) {
    __shared__ int lds[256];
    int v = (threadIdx.x < NBLK) ? bsum[threadIdx.x] : 0;
    lds[threadIdx.x] = v;
    __syncthreads();
    for (int d = 1; d < 256; d <<= 1) {
        int t = (threadIdx.x >= d) ? lds[threadIdx.x - d] : 0;
        __syncthreads();
        lds[threadIdx.x] += t;
        __syncthreads();
    }
    boff[threadIdx.x] = lds[threadIdx.x] - v;   // exclusive
}

__global__ void scanC_kernel(const int* __restrict__ cnt, const int* __restrict__ boff,
                             int* __restrict__ offs) {
    __shared__ int lds[256];
    int i = blockIdx.x * 256 + threadIdx.x;
    int v = (i < NNODES) ? cnt[i] : 0;
    lds[threadIdx.x] = v;
    __syncthreads();
    for (int d = 1; d < 256; d <<= 1) {
        int t = (threadIdx.x >= d) ? lds[threadIdx.x - d] : 0;
        __syncthreads();
        lds[threadIdx.x] += t;
        __syncthreads();
    }
    if (i < NNODES) offs[i] = boff[blockIdx.x] + lds[threadIdx.x] - v;
}

// mode==1 (stream): ebufS payload = (et<<25) | dstslot   (slot < 2^25, et < 2^7)
// mode==0 (atomic): ebufS payload = (et<<16) | dst
__global__ void fill2_kernel(const int* __restrict__ src, const int* __restrict__ dst,
                             const int* __restrict__ et,
                             const int* __restrict__ offsS, const int* __restrict__ offsD,
                             int* __restrict__ curS, int* __restrict__ curD,
                             int* __restrict__ ebufS, int* __restrict__ ebufD, int mode) {
    int e = blockIdx.x * blockDim.x + threadIdx.x;
    if (e < NEDGE) {
        int s = src[e], d = dst[e], t = et[e];
        int pD = atomicAdd(&curD[d], 1);
        int slot = offsD[d] + pD;
        ebufD[slot] = (t << 16) | s;            // by-dst: payload (et, src)
        int pS = atomicAdd(&curS[s], 1);
        int payload = mode ? ((t << 25) | slot) : ((t << 16) | d);
        ebufS[offsS[s] + pS] = payload;
    }
}

// ---------------- weight expansion ----------------

__global__ void wexpand2_kernel(const float* __restrict__ att, const float* __restrict__ basis,
                                float* __restrict__ w2t) {
    int idx = blockIdx.x * blockDim.x + threadIdx.x;
    if (idx >= NREL * 256) return;
    int r = idx >> 8, t = idx & 255, o = t >> 5, i = t & 31;
    float s = 0.f;
    #pragma unroll
    for (int b = 0; b < NB; ++b) s += att[r * NB + b] * basis[b * 256 + i * 8 + o];
    w2t[r * 256 + o * 32 + i] = s;
}

__global__ void wexpand3_kernel(const float* __restrict__ att, const float* __restrict__ basis,
                                float* __restrict__ w3) {
    int idx = blockIdx.x * blockDim.x + threadIdx.x;
    if (idx >= NREL * 8) return;
    int r = idx >> 3, i = idx & 7;
    float s = 0.f;
    #pragma unroll
    for (int b = 0; b < NB; ++b) s += att[r * NB + b] * basis[b * 8 + i];
    w3[idx] = s;
}

// ---------------- layer 1, stream path ----------------

__global__ void layer1_scatter_stream_kernel(const int* __restrict__ ebufS,
                                             const int* __restrict__ offsS,
                                             const int* __restrict__ cntS,
                                             const float* __restrict__ att1,
                                             const float* __restrict__ basis1,
                                             unsigned short* __restrict__ msgh) {
    __shared__ float att_lds[NREL * 32];   // padded rows of 32 for b128 reads
    for (int i = threadIdx.x; i < NREL * NB; i += 256) {
        int r = i / NB, b = i - r * NB;
        att_lds[r * 32 + b] = att1[i];
    }
    __syncthreads();
    int wave = threadIdx.x >> 6, lane = threadIdx.x & 63;
    int s = blockIdx.x * 4 + wave;           // NNODES % 4 == 0
    int o = lane & 31, half = lane >> 5;
    int off = offsS[s], c = cntS[s];
    if (c == 0) return;
    float B[NB];
    const float* bp = basis1 + (size_t)s * 32 + o;
    #pragma unroll
    for (int b = 0; b < NB; ++b) B[b] = bp[(size_t)b * (NNODES * 32)];
    for (int k = half; k < c; k += 2) {
        unsigned p = (unsigned)ebufS[off + k];
        int slot = p & 0x01FFFFFF;
        int et   = p >> 25;
        const float* ar = att_lds + et * 32;   // wave-uniform per half -> broadcast
        float m = 0.f;
        #pragma unroll
        for (int b = 0; b < NB; ++b) m = fmaf(ar[b], B[b], m);
        msgh[(size_t)slot * 32 + o] = __half_as_ushort(__float2half_rn(m));
    }
}

__global__ void layer1_reduce_kernel(const unsigned short* __restrict__ msgh,
                                     const int* __restrict__ offsD, const int* __restrict__ cntD,
                                     const float* __restrict__ root1,
                                     const float* __restrict__ bias1,
                                     float* __restrict__ x1) {
    int wave = threadIdx.x >> 6, lane = threadIdx.x & 63;
    int n = blockIdx.x * 4 + wave;
    int o2 = (lane & 15) * 2, grp = lane >> 4;   // 4 slots in flight per wave
    int off = offsD[n], c = cntD[n];
    float acc0 = 0.f, acc1 = 0.f;
    for (int k = grp; k < c; k += 4) {
        __half2 h = *reinterpret_cast<const __half2*>(msgh + (size_t)(off + k) * 32 + o2);
        float2 f = __half22float2(h);
        acc0 += f.x; acc1 += f.y;
    }
    acc0 += __shfl_xor(acc0, 16); acc0 += __shfl_xor(acc0, 32);
    acc1 += __shfl_xor(acc1, 16); acc1 += __shfl_xor(acc1, 32);
    if (grp == 0) {
        float inv = 1.0f / fmaxf((float)c, 1.0f);
        size_t base = (size_t)n * 32 + o2;
        x1[base]     = fmaxf(acc0 * inv + root1[base]     + bias1[o2],     0.f);
        x1[base + 1] = fmaxf(acc1 * inv + root1[base + 1] + bias1[o2 + 1], 0.f);
    }
}

// ---------------- layer 1, atomic fallback ----------------

__global__ void layer1_scatter_kernel(const int* __restrict__ ebufS, const int* __restrict__ offsS,
                                      const int* __restrict__ cntS, const float* __restrict__ att1,
                                      const float* __restrict__ basis1, float* __restrict__ x1acc) {
    int wave = threadIdx.x >> 6, lane = threadIdx.x & 63;
    int s = blockIdx.x * 4 + wave;
    int o = lane & 31, half = lane >> 5;
    int off = offsS[s], c = cntS[s];
    if (c == 0) return;
    float B[NB];
    const float* bp = basis1 + (size_t)s * 32 + o;
    #pragma unroll
    for (int b = 0; b < NB; ++b) B[b] = bp[(size_t)b * (NNODES * 32)];
    for (int k = half; k < c; k += 2) {
        int p  = ebufS[off + k];
        int d  = p & 0xFFFF, et = p >> 16;
        float attv = (o < NB) ? att1[et * NB + o] : 0.f;
        float m = 0.f;
        #pragma unroll
        for (int b = 0; b < NB; ++b) {
            float a = __shfl(attv, (lane & 32) + b);
            m = fmaf(a, B[b], m);
        }
        atomicAdd(&x1acc[(size_t)d * 32 + o], m);
    }
}

__global__ void layer1_finalize_kernel(const int* __restrict__ cntD,
                                       const float* __restrict__ root1,
                                       const float* __restrict__ bias1,
                                       float* __restrict__ x1) {
    int i = blockIdx.x * 256 + threadIdx.x;
    if (i >= NNODES * 32) return;
    int n = i >> 5, o = i & 31;
    float c = (float)cntD[n];
    float v = x1[i] / fmaxf(c, 1.0f) + root1[i] + bias1[o];
    x1[i] = fmaxf(v, 0.0f);
}

// ---------------- layer 2, src-major msg + dst-ordered reduce ----------------
// wave per src node; o = lane&7, grp = lane>>3 (8 edges in flight).
// x1 row read once (wave-uniform, L1/L2-hot, sequential across waves); stores scatter.

__global__ void layer2_src_msg_kernel(const int* __restrict__ ebufS,
                                      const int* __restrict__ offsS, const int* __restrict__ cntS,
                                      const float* __restrict__ x1, const float* __restrict__ w2t,
                                      float* __restrict__ msg2) {
    int wave = threadIdx.x >> 6, lane = threadIdx.x & 63;
    int s = blockIdx.x * 4 + wave;
    int o = lane & 7, grp = lane >> 3;
    int off = offsS[s], c = cntS[s];
    if (c == 0) return;
    float4 xr[8];
    const float4* xp = (const float4*)(x1 + (size_t)s * 32);
    #pragma unroll
    for (int i = 0; i < 8; ++i) xr[i] = xp[i];
    for (int k0 = 0; k0 < c; k0 += 8) {
        int kk = k0 + grp;
        if (kk < c) {
            unsigned p = (unsigned)ebufS[off + kk];
            int slot = p & 0x01FFFFFF;
            int et   = p >> 25;
            const float4* wp = (const float4*)(w2t + et * 256 + o * 32);
            float acc = 0.f;
            #pragma unroll
            for (int i = 0; i < 8; ++i) {
                float4 wv = wp[i];
                acc += xr[i].x * wv.x + xr[i].y * wv.y + xr[i].z * wv.z + xr[i].w * wv.w;
            }
            msg2[(size_t)slot * 8 + o] = acc;
        }
    }
}

__global__ void layer2_reduce_kernel(const float* __restrict__ msg2,
                                     const int* __restrict__ offsD, const int* __restrict__ cntD,
                                     const float* __restrict__ x1,
                                     const float* __restrict__ root2, const float* __restrict__ bias2,
                                     float* __restrict__ x2) {
    int wave = threadIdx.x >> 6, lane = threadIdx.x & 63;
    int n = blockIdx.x * 4 + wave;
    int o = lane & 7, grp = lane >> 3;
    int off = offsD[n], c = cntD[n];
    float acc = 0.f;
    for (int k = grp; k < c; k += 8) acc += msg2[(size_t)(off + k) * 8 + o];
    #pragma unroll
    for (int d = 8; d < 64; d <<= 1) acc += __shfl_xor(acc, d);
    if (lane < 8) {
        float self = 0.f;
        const float* xn = x1 + (size_t)n * 32;
        #pragma unroll
        for (int i = 0; i < 32; ++i) self += xn[i] * root2[i * 8 + o];
        float v = acc / fmaxf((float)c, 1.0f) + self + bias2[o];
        x2[(size_t)n * 8 + o] = fmaxf(v, 0.0f);
    }
}

// ---------------- layer 3, src-major msg + dst-ordered reduce ----------------
// wave per src node; lane = edge index within node's out-edges.

__global__ void layer3_src_msg_kernel(const int* __restrict__ ebufS,
                                      const int* __restrict__ offsS, const int* __restrict__ cntS,
                                      const float* __restrict__ x2, const float* __restrict__ w3,
                                      float* __restrict__ msg3) {
    int wave = threadIdx.x >> 6, lane = threadIdx.x & 63;
    int s = blockIdx.x * 4 + wave;
    int off = offsS[s], c = cntS[s];
    if (c == 0) return;
    const float4* xp = (const float4*)(x2 + (size_t)s * 8);
    float4 a0 = xp[0], a1 = xp[1];
    for (int k = lane; k < c; k += 64) {
        unsigned p = (unsigned)ebufS[off + k];
        int slot = p & 0x01FFFFFF;
        int et   = p >> 25;
        const float4* wp = (const float4*)(w3 + et * 8);
        float4 b0 = wp[0], b1 = wp[1];
        msg3[slot] = a0.x * b0.x + a0.y * b0.y + a0.z * b0.z + a0.w * b0.w
                   + a1.x * b1.x + a1.y * b1.y + a1.z * b1.z + a1.w * b1.w;
    }
}

__global__ void layer3_reduce_kernel(const float* __restrict__ msg3,
                                     const int* __restrict__ offsD, const int* __restrict__ cntD,
                                     const float* __restrict__ x2,
                                     const float* __restrict__ root3, const float* __restrict__ bias3,
                                     float* __restrict__ out) {
    int wave = threadIdx.x >> 6, lane = threadIdx.x & 63;
    int n = blockIdx.x * 4 + wave;
    int off = offsD[n], c = cntD[n];
    float acc = 0.f;
    for (int k = lane; k < c; k += 64) acc += msg3[off + k];
    #pragma unroll
    for (int d = 1; d < 64; d <<= 1) acc += __shfl_xor(acc, d);
    if (lane == 0) {
        float self = 0.f;
        const float* xn = x2 + (size_t)n * 8;
        #pragma unroll
        for (int i = 0; i < 8; ++i) self += xn[i] * root3[i];
        out[n] = acc / fmaxf((float)c, 1.0f) + self + bias3[0];
    }
}

// ---------------- legacy per-node layers 2/3 (fallback, atomic path) ----------------

__global__ void layer2_kernel(const int* __restrict__ ebufD, const int* __restrict__ offsD,
                              const int* __restrict__ cntD,
                              const float* __restrict__ x1, const float* __restrict__ w2t,
                              const float* __restrict__ root2, const float* __restrict__ bias2,
                              float* __restrict__ x2) {
    int wave = threadIdx.x >> 6, lane = threadIdx.x & 63;
    int n = blockIdx.x * 4 + wave;
    int o = lane & 7, slot = lane >> 3;
    int off = offsD[n], c = cntD[n];
    float acc = 0.f;
    for (int k0 = 0; k0 < c; k0 += 8) {
        int kk = k0 + slot;
        if (kk < c) {
            int packed = ebufD[off + kk];
            int src = packed & 0xFFFF, et = packed >> 16;
            const float4* xp = (const float4*)(x1 + (size_t)src * 32);
            const float4* wp = (const float4*)(w2t + et * 256 + o * 32);
            #pragma unroll
            for (int i = 0; i < 8; ++i) {
                float4 xv = xp[i], wv = wp[i];
                acc += xv.x * wv.x + xv.y * wv.y + xv.z * wv.z + xv.w * wv.w;
            }
        }
    }
    #pragma unroll
    for (int d = 8; d < 64; d <<= 1) acc += __shfl_xor(acc, d);
    if (lane < 8) {
        float self = 0.f;
        const float* xn = x1 + (size_t)n * 32;
        #pragma unroll
        for (int i = 0; i < 32; ++i) self += xn[i] * root2[i * 8 + o];
        float v = acc / fmaxf((float)c, 1.0f) + self + bias2[o];
        x2[(size_t)n * 8 + o] = fmaxf(v, 0.0f);
    }
}

__global__ void layer3_kernel(const int* __restrict__ ebufD, const int* __restrict__ offsD,
                              const int* __restrict__ cntD,
                              const float* __restrict__ x2, const float* __restrict__ w3,
                              const float* __restrict__ root3, const float* __restrict__ bias3,
                              float* __restrict__ out) {
    int wave = threadIdx.x >> 6, lane = threadIdx.x & 63;
    int n = blockIdx.x * 4 + wave;
    int off = offsD[n], c = cntD[n];
    float acc = 0.f;
    for (int k = lane; k < c; k += 64) {
        int packed = ebufD[off + k];
        int src = packed & 0xFFFF, et = packed >> 16;
        const float4* xp = (const float4*)(x2 + src * 8);
        const float4* wp = (const float4*)(w3 + et * 8);
        float4 a0 = xp[0], a1 = xp[1], b0 = wp[0], b1 = wp[1];
        acc += a0.x * b0.x + a0.y * b0.y + a0.z * b0.z + a0.w * b0.w
             + a1.x * b1.x + a1.y * b1.y + a1.z * b1.z + a1.w * b1.w;
    }
    #pragma unroll
    for (int d = 1; d < 64; d <<= 1) acc += __shfl_xor(acc, d);
    if (lane == 0) {
        float self = 0.f;
        const float* xn = x2 + (size_t)n * 8;
        #pragma unroll
        for (int i = 0; i < 8; ++i) self += xn[i] * root3[i];
        out[n] = acc / fmaxf((float)c, 1.0f) + self + bias3[0];
    }
}

// ---------------- launch ----------------

extern "C" void kernel_launch(void* const* d_in, const int* in_sizes, int n_in,
                              void* d_out, int out_size, void* d_ws, size_t ws_size,
                              hipStream_t stream) {
    const int*   edge_index = (const int*)  d_in[0];
    const int*   edge_type  = (const int*)  d_in[1];
    const float* att1   = (const float*) d_in[2];
    const float* basis1 = (const float*) d_in[3];
    const float* root1  = (const float*) d_in[4];
    const float* bias1  = (const float*) d_in[5];
    const float* att2   = (const float*) d_in[6];
    const float* basis2 = (const float*) d_in[7];
    const float* root2  = (const float*) d_in[8];
    const float* bias2  = (const float*) d_in[9];
    const float* att3   = (const float*) d_in[10];
    const float* basis3 = (const float*) d_in[11];
    const float* root3  = (const float*) d_in[12];
    const float* bias3  = (const float*) d_in[13];
    float* out = (float*)d_out;

    const int* srcArr = edge_index;
    const int* dstArr = edge_index + NEDGE;

    char* ws = (char*)d_ws;
    int*   cntS   = (int*)(ws + 0);              // 240,000
    int*   cntD   = (int*)(ws + 240128);         // 240,000
    int*   offsS  = (int*)(ws + 480256);         // 240,000
    int*   offsD  = (int*)(ws + 720384);         // 240,000
    int*   bsum   = (int*)(ws + 960512);         // 1,024
    int*   boff   = (int*)(ws + 961536);         // 1,024
    int*   curS   = (int*)(ws + 962560);         // 240,000
    int*   curD   = (int*)(ws + 1202688);        // 240,000
    int*   ebufS  = (int*)(ws + 1442816);        // 7,680,000
    int*   ebufD  = (int*)(ws + 9122816);        // 7,680,000
    float* w2t    = (float*)(ws + 16802816);     // 71,680
    float* w3     = (float*)(ws + 16874496);     // 2,240
    float* x1     = (float*)(ws + 16877056);     // 7,680,000
    float* x2     = (float*)(ws + 24557056);     // 1,920,000  -> end 26,477,056
    unsigned short* msgh = (unsigned short*)(ws + 26477056);  // 122,880,000 -> end 149,357,056
    float* msg2   = (float*)(ws + 26477056);     // 61,440,000 (reuses msgh region after l1 reduce)
    float* msg3   = (float*)(ws + 87917056);     // 7,680,000  -> end 95,597,056
    const bool use_stream = ws_size >= 149357056ULL;

    // zero histograms + cursors
    hipMemsetAsync(ws, 0, 480128, stream);              // cntS + cntD
    hipMemsetAsync(ws + 962560, 0, 480128, stream);     // curS + curD

    // CSR build (both directions)
    hist2_kernel<<<NEDGE / 256, 256, 0, stream>>>(srcArr, dstArr, cntS, cntD);
    scanA_kernel<<<NBLK, 256, 0, stream>>>(cntS, bsum);
    scanB_kernel<<<1, 256, 0, stream>>>(bsum, boff);
    scanC_kernel<<<NBLK, 256, 0, stream>>>(cntS, boff, offsS);
    scanA_kernel<<<NBLK, 256, 0, stream>>>(cntD, bsum);
    scanB_kernel<<<1, 256, 0, stream>>>(bsum, boff);
    scanC_kernel<<<NBLK, 256, 0, stream>>>(cntD, boff, offsD);
    fill2_kernel<<<NEDGE / 256, 256, 0, stream>>>(srcArr, dstArr, edge_type,
                                                  offsS, offsD, curS, curD, ebufS, ebufD,
                                                  use_stream ? 1 : 0);

    // weight expansion
    wexpand2_kernel<<<(NREL * 256 + 255) / 256, 256, 0, stream>>>(att2, basis2, w2t);
    wexpand3_kernel<<<(NREL * 8 + 255) / 256, 256, 0, stream>>>(att3, basis3, w3);

    // layer 1
    if (use_stream) {
        layer1_scatter_stream_kernel<<<NNODES / 4, 256, 0, stream>>>(ebufS, offsS, cntS,
                                                                     att1, basis1, msgh);
        layer1_reduce_kernel<<<NNODES / 4, 256, 0, stream>>>(msgh, offsD, cntD, root1, bias1, x1);
    } else {
        hipMemsetAsync((void*)x1, 0, 7680000, stream);
        layer1_scatter_kernel<<<NNODES / 4, 256, 0, stream>>>(ebufS, offsS, cntS, att1, basis1, x1);
        layer1_finalize_kernel<<<(NNODES * 32) / 256, 256, 0, stream>>>(cntD, root1, bias1, x1);
    }

    // layers 2, 3
    if (use_stream) {
        layer2_src_msg_kernel<<<NNODES / 4, 256, 0, stream>>>(ebufS, offsS, cntS, x1, w2t, msg2);
        layer2_reduce_kernel<<<NNODES / 4, 256, 0, stream>>>(msg2, offsD, cntD, x1, root2, bias2, x2);
        layer3_src_msg_kernel<<<NNODES / 4, 256, 0, stream>>>(ebufS, offsS, cntS, x2, w3, msg3);
        layer3_reduce_kernel<<<NNODES / 4, 256, 0, stream>>>(msg3, offsD, cntD, x2, root3, bias3, out);
    } else {
        layer2_kernel<<<NNODES / 4, 256, 0, stream>>>(ebufD, offsD, cntD, x1, w2t, root2, bias2, x2);
        layer3_kernel<<<NNODES / 4, 256, 0, stream>>>(ebufD, offsD, cntD, x2, w3, root3, bias3, out);
    }
}